// Round 5
// baseline (1471.584 us; speedup 1.0000x reference)
//
#include <hip/hip_runtime.h>

#define BB 512
#define TT 2048
#define II 8
#define HH 128
#define OO 96

typedef __attribute__((ext_vector_type(8))) short bf16x8;
typedef __attribute__((ext_vector_type(4))) float f32x4;

__device__ __forceinline__ float fast_rcp(float x) { return __builtin_amdgcn_rcpf(x); }
__device__ __forceinline__ float sigmoid_fast(float x) { return fast_rcp(1.0f + __expf(-x)); }
__device__ __forceinline__ float tanh_fast(float x) {
    return 1.0f - 2.0f * fast_rcp(1.0f + __expf(2.0f * x));
}
__device__ __forceinline__ unsigned short f2bf(float f) {
    unsigned int u = __builtin_bit_cast(unsigned int, f);
    u += 0x7fffu + ((u >> 16) & 1u);   // RNE
    return (unsigned short)(u >> 16);
}
__device__ __forceinline__ float bf2f(unsigned short h) {
    unsigned int u = ((unsigned int)h) << 16;
    return __builtin_bit_cast(float, u);
}

// One block = 8 waves = ONE batch row; grid = 512 blocks -> 2 independent
// blocks per CU (own barriers) so their latency chains interleave.
// A tile: rows m: even=h_hi, odd=h_lo (x8 replicated), k=[h(128)|x(8)|0(24)].
// gh = C[0] + C[1] in every lane (bf16 split compensation).
// LDS: 2 bufs x 2 planes x 320B.
__global__ __launch_bounds__(512, 4) void gru_kernel(
    const float* __restrict__ x,     // [B, T, I]
    const float* __restrict__ w_ih,  // [3H, I]
    const float* __restrict__ w_hh,  // [3H, H]
    const float* __restrict__ b_ih,  // [3H]
    const float* __restrict__ b_hh,  // [3H]
    const float* __restrict__ fc_w,  // [O, H]
    const float* __restrict__ fc_b,  // [O]
    float* __restrict__ out)         // [B, O]
{
    __shared__ __align__(16) char hbuf[2 * 640];
    __shared__ __align__(16) float hfin[HH];

    const int tid = threadIdx.x;
    const int wv  = tid >> 6;
    const int ln  = tid & 63;
    const int col = ln & 15;
    const int g4  = ln >> 4;
    const int j   = 16 * wv + col;
    const int b   = blockIdx.x;

    // ---- B fragments (weights -> bf16, weight-stationary) ----
    auto ldfrag_hh = [&](int grow, int ks) {
        const float* rowp = w_hh + grow * HH + 32 * ks + g4 * 8;
        float4 u = *(const float4*)(rowp);
        float4 v = *(const float4*)(rowp + 4);
        bf16x8 f;
        f[0] = (short)f2bf(u.x); f[1] = (short)f2bf(u.y);
        f[2] = (short)f2bf(u.z); f[3] = (short)f2bf(u.w);
        f[4] = (short)f2bf(v.x); f[5] = (short)f2bf(v.y);
        f[6] = (short)f2bf(v.z); f[7] = (short)f2bf(v.w);
        return f;
    };
    auto ldfrag_ih = [&](int grow) {
        bf16x8 f = {0, 0, 0, 0, 0, 0, 0, 0};
        if (g4 == 0) {
            const float* rowp = w_ih + grow * II;
            float4 u = *(const float4*)(rowp);
            float4 v = *(const float4*)(rowp + 4);
            f[0] = (short)f2bf(u.x); f[1] = (short)f2bf(u.y);
            f[2] = (short)f2bf(u.z); f[3] = (short)f2bf(u.w);
            f[4] = (short)f2bf(v.x); f[5] = (short)f2bf(v.y);
            f[6] = (short)f2bf(v.z); f[7] = (short)f2bf(v.w);
        }
        return f;
    };

    bf16x8 bR[5], bZ[5], bN[4], bX;
#pragma unroll
    for (int ks = 0; ks < 4; ++ks) {
        bR[ks] = ldfrag_hh(j, ks);
        bZ[ks] = ldfrag_hh(HH + j, ks);
        bN[ks] = ldfrag_hh(2 * HH + j, ks);
    }
    bR[4] = ldfrag_ih(j);
    bZ[4] = ldfrag_ih(HH + j);
    bX    = ldfrag_ih(2 * HH + j);

    const float bias_r  = b_ih[j] + b_hh[j];
    const float bias_z  = b_ih[HH + j] + b_hh[HH + j];
    const float bias_nh = b_hh[2 * HH + j];
    const float bias_nx = b_ih[2 * HH + j];

    // ---- zero LDS (h = 0, k-pad = 0, both buffers) ----
    for (int i = tid; i < 320; i += 512) ((int*)hbuf)[i] = 0;
    __syncthreads();

    // ---- x staging: wave 7 lanes 0..7 (lane = i) ----
    const float* xr = x + (size_t)b * TT * II + ln;
    float xc1 = 0.f, xc2 = 0.f;
    if (wv == 7 && ln < 8) {
        float x0 = xr[0];
        xc1 = xr[II];
        xc2 = xr[2 * II];
        unsigned short xh = f2bf(x0);
        char* xw = hbuf + (128 + ln) * 2;            // buf0, plane0 (hi)
        *(unsigned short*)(xw)       = xh;
        *(unsigned short*)(xw + 320) = f2bf(x0 - bf2f(xh));  // plane1 (lo)
    }
    __syncthreads();

    const char* abase = hbuf + (ln & 1) * 320 + g4 * 16;  // plane = row parity
    char* hw = hbuf + j * 2;
    float h0 = 0.f;
    const f32x4 zf = {0.f, 0.f, 0.f, 0.f};

#define STEP(BUF, XVAL)                                                         \
    {                                                                           \
        const char* ab = abase + (BUF) * 640;                                   \
        bf16x8 a0 = *(const bf16x8*)(ab);                                       \
        bf16x8 a1 = *(const bf16x8*)(ab + 64);                                  \
        bf16x8 a2 = *(const bf16x8*)(ab + 128);                                 \
        bf16x8 a3 = *(const bf16x8*)(ab + 192);                                 \
        bf16x8 a4 = *(const bf16x8*)(ab + 256);                                 \
        /* split chains: depth <= 3 per gate */                                 \
        f32x4 r1 = __builtin_amdgcn_mfma_f32_16x16x32_bf16(a4, bR[4], zf, 0, 0, 0); \
        f32x4 z1 = __builtin_amdgcn_mfma_f32_16x16x32_bf16(a4, bZ[4], zf, 0, 0, 0); \
        f32x4 xx = __builtin_amdgcn_mfma_f32_16x16x32_bf16(a4, bX,    zf, 0, 0, 0); \
        f32x4 n1 = __builtin_amdgcn_mfma_f32_16x16x32_bf16(a0, bN[0], zf, 0, 0, 0); \
        f32x4 r2 = __builtin_amdgcn_mfma_f32_16x16x32_bf16(a2, bR[2], zf, 0, 0, 0); \
        f32x4 z2 = __builtin_amdgcn_mfma_f32_16x16x32_bf16(a2, bZ[2], zf, 0, 0, 0); \
        f32x4 n2 = __builtin_amdgcn_mfma_f32_16x16x32_bf16(a2, bN[2], zf, 0, 0, 0); \
        r1 = __builtin_amdgcn_mfma_f32_16x16x32_bf16(a0, bR[0], r1, 0, 0, 0);   \
        z1 = __builtin_amdgcn_mfma_f32_16x16x32_bf16(a0, bZ[0], z1, 0, 0, 0);   \
        n1 = __builtin_amdgcn_mfma_f32_16x16x32_bf16(a1, bN[1], n1, 0, 0, 0);   \
        r2 = __builtin_amdgcn_mfma_f32_16x16x32_bf16(a3, bR[3], r2, 0, 0, 0);   \
        z2 = __builtin_amdgcn_mfma_f32_16x16x32_bf16(a3, bZ[3], z2, 0, 0, 0);   \
        n2 = __builtin_amdgcn_mfma_f32_16x16x32_bf16(a3, bN[3], n2, 0, 0, 0);   \
        r1 = __builtin_amdgcn_mfma_f32_16x16x32_bf16(a1, bR[1], r1, 0, 0, 0);   \
        z1 = __builtin_amdgcn_mfma_f32_16x16x32_bf16(a1, bZ[1], z1, 0, 0, 0);   \
        float gr = (r1[0] + r1[1]) + (r2[0] + r2[1]) + bias_r;                  \
        float gz = (z1[0] + z1[1]) + (z2[0] + z2[1]) + bias_z;                  \
        float gn = (n1[0] + n1[1]) + (n2[0] + n2[1]) + bias_nh;                 \
        float gx = (xx[0] + xx[1]) + bias_nx;                                   \
        float r0 = sigmoid_fast(gr);                                            \
        float z0 = sigmoid_fast(gz);                                            \
        float n0 = tanh_fast(fmaf(r0, gn, gx));                                 \
        h0 = fmaf(z0, h0 - n0, n0);                                             \
        if (ln < 16) {                                                          \
            char* w_ = hw + (1 - (BUF)) * 640;                                  \
            unsigned short s0 = f2bf(h0);                                       \
            *(unsigned short*)(w_)       = s0;                                  \
            *(unsigned short*)(w_ + 320) = f2bf(h0 - bf2f(s0));                 \
        }                                                                       \
        if (wv == 7 && ln < 8) {                                                \
            unsigned short xh = f2bf(XVAL);                                     \
            char* xw = hbuf + (1 - (BUF)) * 640 + (128 + ln) * 2;               \
            *(unsigned short*)(xw)       = xh;                                  \
            *(unsigned short*)(xw + 320) = f2bf((XVAL) - bf2f(xh));             \
        }                                                                       \
        __syncthreads();                                                        \
    }

    for (int it = 0; it < TT / 2; ++it) {
        float xn1 = 0.f, xn2 = 0.f;
        if (wv == 7 && ln < 8) {                    // prefetch x(t+3), x(t+4)
            int t3 = 2 * it + 3; if (t3 >= TT) t3 = TT - 1;
            int t4 = 2 * it + 4; if (t4 >= TT) t4 = TT - 1;
            xn1 = xr[t3 * II];
            xn2 = xr[t4 * II];
        }
        STEP(0, xc1)
        STEP(1, xc2)
        xc1 = xn1; xc2 = xn2;
    }
#undef STEP

    // ---- epilogue FC ----
    if (ln < 16) hfin[j] = h0;   // g4==0 lanes of EVERY wave: covers j=0..127
    __syncthreads();

    if (tid < OO) {
        const int o = tid;
        const float4* hf = (const float4*)(&hfin[0]);
        const float4* wp = (const float4*)(fc_w + o * HH);
        float acc = fc_b[o];
#pragma unroll 8
        for (int v = 0; v < HH / 4; ++v) {
            float4 w4 = wp[v];
            float4 h4 = hf[v];
            acc = fmaf(w4.x, h4.x, acc); acc = fmaf(w4.y, h4.y, acc);
            acc = fmaf(w4.z, h4.z, acc); acc = fmaf(w4.w, h4.w, acc);
        }
        out[(size_t)b * OO + o] = acc;
    }
}

extern "C" void kernel_launch(void* const* d_in, const int* in_sizes, int n_in,
                              void* d_out, int out_size, void* d_ws, size_t ws_size,
                              hipStream_t stream) {
    const float* x    = (const float*)d_in[0];
    const float* w_ih = (const float*)d_in[1];
    const float* w_hh = (const float*)d_in[2];
    const float* b_ih = (const float*)d_in[3];
    const float* b_hh = (const float*)d_in[4];
    const float* fc_w = (const float*)d_in[5];
    const float* fc_b = (const float*)d_in[6];
    float* out = (float*)d_out;

    gru_kernel<<<BB, 512, 0, stream>>>(x, w_ih, w_hh, b_ih, b_hh, fc_w, fc_b, out);
}